// Round 1
// baseline (757.515 us; speedup 1.0000x reference)
//
#include <hip/hip_runtime.h>
#include <hip/hip_bf16.h>

#define BB 8192
#define MM 64
#define DD 256
#define NEGV -1e9f

// ---------------------------------------------------------------------------
// Kernel A: per-sample masked attention over ragged memory.
//   One block (4 waves) per sample b. mem[b] (64x256 fp32, 64KB from HBM) is
//   read ONCE; a bf16 copy (32KB) is staged in LDS for the r = attn·mem pass.
//   Scores are fp32 dots computed from the same in-flight loads via
//   wave-shuffle reduction. Softmax in wave 0. r written fp32 to workspace.
// ---------------------------------------------------------------------------
__global__ __launch_bounds__(256) void attn_kernel(
    const float* __restrict__ h, const float* __restrict__ mem,
    const int* __restrict__ len, float* __restrict__ r_out)
{
    __shared__ __hip_bfloat16 tile[MM * DD];   // 32 KB bf16 copy of mem[b]
    __shared__ float score_s[MM];
    __shared__ float attn_s[MM];

    const int b    = blockIdx.x;
    const int t    = threadIdx.x;
    const int lane = t & 63;
    const int wave = t >> 6;
    const int L    = len[b];

    // each lane holds h[b, 4*lane .. 4*lane+3]
    const float4 hv = *reinterpret_cast<const float4*>(h + (size_t)b * DD + 4 * lane);
    const float* mbase = mem + (size_t)b * MM * DD;

    #pragma unroll
    for (int i = 0; i < 16; ++i) {
        const int m = wave * 16 + i;
        const float4 v = *reinterpret_cast<const float4*>(mbase + m * DD + 4 * lane);

        // stash bf16 copy in LDS (two b32 stores, conflict-free)
        __hip_bfloat162* t2 =
            reinterpret_cast<__hip_bfloat162*>(tile + m * DD + 4 * lane);
        __hip_bfloat162 p0, p1;
        p0.x = __float2bfloat16(v.x); p0.y = __float2bfloat16(v.y);
        p1.x = __float2bfloat16(v.z); p1.y = __float2bfloat16(v.w);
        t2[0] = p0; t2[1] = p1;

        // fp32 partial dot, reduce across the 64-lane wave
        float p = v.x * hv.x + v.y * hv.y + v.z * hv.z + v.w * hv.w;
        #pragma unroll
        for (int off = 32; off > 0; off >>= 1)
            p += __shfl_xor(p, off, 64);
        if (lane == 0) score_s[m] = (m < L) ? p : NEGV;
    }
    __syncthreads();

    // masked softmax over the 64 scores: wave 0, lane == m.
    // L == 0: all scores NEG -> uniform attn (harmless; kernel B passes h thru)
    if (wave == 0) {
        const float s = score_s[lane];
        float mx = s;
        #pragma unroll
        for (int off = 32; off > 0; off >>= 1)
            mx = fmaxf(mx, __shfl_xor(mx, off, 64));
        const float e = __expf(s - mx);
        float den = e;
        #pragma unroll
        for (int off = 32; off > 0; off >>= 1)
            den += __shfl_xor(den, off, 64);
        attn_s[lane] = e / den;
    }
    __syncthreads();

    // r[t] = sum_m attn[m] * mem[b, m, t]; attn_s is broadcast (free),
    // tile column reads are 2 lanes/word (free).
    float acc = 0.f;
    #pragma unroll
    for (int m = 0; m < MM; ++m)
        acc += attn_s[m] * __bfloat162float(tile[m * DD + t]);
    r_out[(size_t)b * DD + t] = acc;
}

// ---------------------------------------------------------------------------
// Kernel B: gating GEMMs + blend.
//   out[b,d] = blend( sigmoid( h·Wg^T + r·Ug^T + biases ), r, h, len )
//   Classic fp32 SGEMM: 64x64 output tile per block, 256 threads, each thread
//   a 4x4 micro-tile; K loop runs over two phases (h/Wg then r/Ug), staging
//   64x32 tiles in LDS with +1 padding (a-reads broadcast, w-reads 2-way).
// ---------------------------------------------------------------------------
__global__ __launch_bounds__(256) void gate_kernel(
    const float* __restrict__ h, const float* __restrict__ r,
    const int* __restrict__ len,
    const float* __restrict__ Wg_w, const float* __restrict__ Wg_b,
    const float* __restrict__ Ug_w, const float* __restrict__ Ug_b,
    const float* __restrict__ b_g, float* __restrict__ out)
{
    __shared__ float As[64][33];
    __shared__ float Ws[64][33];

    const int t     = threadIdx.x;
    const int brow0 = blockIdx.x * 64;
    const int dcol0 = blockIdx.y * 64;
    const int ty = t >> 4;          // 0..15 -> output rows 4*ty..+3
    const int tx = t & 15;          // 0..15 -> output cols 4*tx..+3

    const int lrow = t >> 3;        // staging: row 0..31 (+32 for second half)
    const int lc4  = (t & 7) * 4;   // staging: 16B column group

    float acc[4][4] = {};

    for (int phase = 0; phase < 2; ++phase) {
        const float* A = phase ? r : h;
        const float* W = phase ? Ug_w : Wg_w;
        for (int k0 = 0; k0 < DD; k0 += 32) {
            #pragma unroll
            for (int half = 0; half < 2; ++half) {
                const int row = lrow + 32 * half;
                const float4 av = *reinterpret_cast<const float4*>(
                    A + (size_t)(brow0 + row) * DD + k0 + lc4);
                As[row][lc4 + 0] = av.x; As[row][lc4 + 1] = av.y;
                As[row][lc4 + 2] = av.z; As[row][lc4 + 3] = av.w;
                const float4 wv = *reinterpret_cast<const float4*>(
                    W + (size_t)(dcol0 + row) * DD + k0 + lc4);
                Ws[row][lc4 + 0] = wv.x; Ws[row][lc4 + 1] = wv.y;
                Ws[row][lc4 + 2] = wv.z; Ws[row][lc4 + 3] = wv.w;
            }
            __syncthreads();
            #pragma unroll
            for (int kk = 0; kk < 32; ++kk) {
                float a[4], w[4];
                #pragma unroll
                for (int i = 0; i < 4; ++i) a[i] = As[4 * ty + i][kk];
                #pragma unroll
                for (int j = 0; j < 4; ++j) w[j] = Ws[4 * tx + j][kk];
                #pragma unroll
                for (int i = 0; i < 4; ++i)
                    #pragma unroll
                    for (int j = 0; j < 4; ++j)
                        acc[i][j] += a[i] * w[j];
            }
            __syncthreads();
        }
    }

    // epilogue: biases, sigmoid, blend, empty-memory passthrough
    #pragma unroll
    for (int i = 0; i < 4; ++i) {
        const int bb = brow0 + 4 * ty + i;
        const int lb = len[bb];
        #pragma unroll
        for (int j = 0; j < 4; ++j) {
            const int d = dcol0 + 4 * tx + j;
            const float x = acc[i][j] + Wg_b[d] + Ug_b[d] + b_g[d];
            const float g = 1.f / (1.f + __expf(-x));
            const size_t idx = (size_t)bb * DD + d;
            const float rv = r[idx];
            const float hv = h[idx];
            out[idx] = (lb > 0) ? (g * rv + (1.f - g) * hv) : hv;
        }
    }
}

extern "C" void kernel_launch(void* const* d_in, const int* in_sizes, int n_in,
                              void* d_out, int out_size, void* d_ws, size_t ws_size,
                              hipStream_t stream) {
    const float* h    = (const float*)d_in[0];
    const float* mem  = (const float*)d_in[1];
    const int*   len  = (const int*)d_in[2];
    const float* Wg_w = (const float*)d_in[3];
    const float* Wg_b = (const float*)d_in[4];
    const float* Ug_w = (const float*)d_in[5];
    const float* Ug_b = (const float*)d_in[6];
    const float* b_g  = (const float*)d_in[7];
    float* out  = (float*)d_out;
    float* r_ws = (float*)d_ws;   // needs B*D*4 = 8 MiB of scratch for r

    attn_kernel<<<BB, 256, 0, stream>>>(h, mem, len, r_ws);
    gate_kernel<<<dim3(BB / 64, DD / 64), 256, 0, stream>>>(
        h, r_ws, len, Wg_w, Wg_b, Ug_w, Ug_b, b_g, out);
}

// Round 2
// 715.592 us; speedup vs baseline: 1.0586x; 1.0586x over previous
//
#include <hip/hip_runtime.h>
#include <hip/hip_bf16.h>

#define BB 8192
#define MM 64
#define DD 256
#define NEGV -1e9f
#define TSTR 260   // LDS tile row stride in bf16 elements (520 B: 8B-aligned, conflict-benign)

typedef __attribute__((ext_vector_type(8))) short frag_ab;  // 8 bf16 = 4 VGPRs
typedef __attribute__((ext_vector_type(4))) float f32x4;

struct __align__(8) bfq { __hip_bfloat162 lo, hi; };

__device__ inline short f2bs(float f) {
    __hip_bfloat16 v = __float2bfloat16(f);
    return *reinterpret_cast<short*>(&v);
}

// ---------------------------------------------------------------------------
// Kernel A: per-sample masked attention. One block per sample.
//   Thread t owns row m=t>>2, 64-col chunk c=t&3: fp32 score partials reduce
//   with TWO quad-perm shuffles (VALU DPP) instead of 6 LDS swizzle stages.
//   bf16 tile staged to LDS (b64 writes) for the r = attn·mem pass.
// ---------------------------------------------------------------------------
__global__ __launch_bounds__(256) void attn_kernel(
    const float* __restrict__ h, const float* __restrict__ mem,
    const int* __restrict__ len, float* __restrict__ r_out)
{
    __shared__ __hip_bfloat16 tile[MM * TSTR];          // 33.3 KB
    __shared__ __align__(16) float h_s[DD];
    __shared__ float score_s[MM];
    __shared__ __align__(16) float attn_s[MM];

    const int b = blockIdx.x;
    const int t = threadIdx.x;
    const int m = t >> 2;      // row 0..63
    const int c = t & 3;       // 64-col chunk
    const int L = len[b];

    h_s[t] = h[(size_t)b * DD + t];
    __syncthreads();

    const float* mrow = mem + (size_t)b * MM * DD + (size_t)m * DD + c * 64;
    __hip_bfloat16* trow = tile + m * TSTR + c * 64;

    float p = 0.f;
    #pragma unroll
    for (int j = 0; j < 16; ++j) {
        const float4 v  = *reinterpret_cast<const float4*>(mrow + 4 * j);
        const float4 hv = *reinterpret_cast<const float4*>(h_s + c * 64 + 4 * j); // broadcast
        p += v.x * hv.x + v.y * hv.y + v.z * hv.z + v.w * hv.w;
        bfq q;
        q.lo = __float22bfloat162_rn(float2{v.x, v.y});
        q.hi = __float22bfloat162_rn(float2{v.z, v.w});
        *reinterpret_cast<bfq*>(trow + 4 * j) = q;      // ds_write_b64
    }
    // reduce the 4 chunk-partials (lanes 4m..4m+3): cheap quad-perm shuffles
    p += __shfl_xor(p, 1, 64);
    p += __shfl_xor(p, 2, 64);
    if (c == 0) score_s[m] = (m < L) ? p : NEGV;
    __syncthreads();

    // masked softmax over 64 scores: wave 0 only (once per block)
    if (t < 64) {
        const float s = score_s[t];
        float mx = s;
        #pragma unroll
        for (int off = 32; off > 0; off >>= 1)
            mx = fmaxf(mx, __shfl_xor(mx, off, 64));
        const float e = __expf(s - mx);
        float den = e;
        #pragma unroll
        for (int off = 32; off > 0; off >>= 1)
            den += __shfl_xor(den, off, 64);
        attn_s[t] = e / den;
    }
    __syncthreads();

    // r[d=t] = sum_m attn[m] * tile[m][t]; attn via broadcast b128 into regs
    float acc = 0.f;
    #pragma unroll
    for (int mc = 0; mc < 16; ++mc) {
        const float4 aw = *reinterpret_cast<const float4*>(attn_s + 4 * mc);
        acc += aw.x * __bfloat162float(tile[(4 * mc + 0) * TSTR + t]);
        acc += aw.y * __bfloat162float(tile[(4 * mc + 1) * TSTR + t]);
        acc += aw.z * __bfloat162float(tile[(4 * mc + 2) * TSTR + t]);
        acc += aw.w * __bfloat162float(tile[(4 * mc + 3) * TSTR + t]);
    }
    r_out[(size_t)b * DD + t] = acc;
}

// ---------------------------------------------------------------------------
// Kernel B: gating GEMMs + blend via bf16 MFMA 16x16x32 (B^T pattern).
//   C[b,d] = h·Wg^T + r·Ug^T over K=2x256. 64x64 tile per block, 4 waves,
//   wave w owns rows 16w..16w+15 x all 64 cols (4 accumulators).
// ---------------------------------------------------------------------------
__global__ __launch_bounds__(256) void gate_kernel(
    const float* __restrict__ h, const float* __restrict__ r,
    const int* __restrict__ len,
    const float* __restrict__ Wg_w, const float* __restrict__ Wg_b,
    const float* __restrict__ Ug_w, const float* __restrict__ Ug_b,
    const float* __restrict__ b_g, float* __restrict__ out)
{
    __shared__ __hip_bfloat16 Abuf[64 * 32];   // 4 KB
    __shared__ __hip_bfloat16 Wbuf[64 * 32];   // 4 KB

    const int t    = threadIdx.x;
    const int lane = t & 63;
    const int wave = t >> 6;
    const int brow0 = blockIdx.x * 64;
    const int dcol0 = blockIdx.y * 64;

    const int srow = t >> 2;     // staging row 0..63
    const int skq  = t & 3;      // staging k-octet

    const f32x4 zero = {0.f, 0.f, 0.f, 0.f};
    f32x4 acc[4];
    #pragma unroll
    for (int ct = 0; ct < 4; ++ct) acc[ct] = zero;

    const int arow_m = (lane & 15);          // MFMA A row within 16-tile
    const int kchunk = (lane >> 4) * 8;      // MFMA k-octet within BK=32

    for (int phase = 0; phase < 2; ++phase) {
        const float* Ag = phase ? r : h;
        const float* Wg = phase ? Ug_w : Wg_w;
        const float* ap = Ag + (size_t)(brow0 + srow) * DD + skq * 8;
        const float* wp = Wg + (size_t)(dcol0 + srow) * DD + skq * 8;

        for (int k0 = 0; k0 < DD; k0 += 32) {
            const float4 a0 = *reinterpret_cast<const float4*>(ap + k0);
            const float4 a1 = *reinterpret_cast<const float4*>(ap + k0 + 4);
            const float4 w0 = *reinterpret_cast<const float4*>(wp + k0);
            const float4 w1 = *reinterpret_cast<const float4*>(wp + k0 + 4);

            __syncthreads();   // previous step's frags fully read
            frag_ab av, wv;
            av[0] = f2bs(a0.x); av[1] = f2bs(a0.y); av[2] = f2bs(a0.z); av[3] = f2bs(a0.w);
            av[4] = f2bs(a1.x); av[5] = f2bs(a1.y); av[6] = f2bs(a1.z); av[7] = f2bs(a1.w);
            wv[0] = f2bs(w0.x); wv[1] = f2bs(w0.y); wv[2] = f2bs(w0.z); wv[3] = f2bs(w0.w);
            wv[4] = f2bs(w1.x); wv[5] = f2bs(w1.y); wv[6] = f2bs(w1.z); wv[7] = f2bs(w1.w);
            *reinterpret_cast<frag_ab*>(&Abuf[srow * 32 + skq * 8]) = av;
            *reinterpret_cast<frag_ab*>(&Wbuf[srow * 32 + skq * 8]) = wv;
            __syncthreads();

            const frag_ab af = *reinterpret_cast<const frag_ab*>(
                &Abuf[(wave * 16 + arow_m) * 32 + kchunk]);
            #pragma unroll
            for (int ct = 0; ct < 4; ++ct) {
                const frag_ab wf = *reinterpret_cast<const frag_ab*>(
                    &Wbuf[(ct * 16 + arow_m) * 32 + kchunk]);
                acc[ct] = __builtin_amdgcn_mfma_f32_16x16x32_bf16(af, wf, acc[ct], 0, 0, 0);
            }
        }
    }

    // epilogue: bias + sigmoid + blend + empty-memory passthrough
    // C/D layout: col = lane&15, row = (lane>>4)*4 + reg
    float bias_v[4];
    #pragma unroll
    for (int ct = 0; ct < 4; ++ct) {
        const int d = dcol0 + ct * 16 + (lane & 15);
        bias_v[ct] = Wg_b[d] + Ug_b[d] + b_g[d];
    }
    const int rbase = brow0 + wave * 16 + (lane >> 4) * 4;
    #pragma unroll
    for (int i = 0; i < 4; ++i) {
        const int bb = rbase + i;
        const int lb = len[bb];
        #pragma unroll
        for (int ct = 0; ct < 4; ++ct) {
            const int d = dcol0 + ct * 16 + (lane & 15);
            const float x = acc[ct][i] + bias_v[ct];
            const float g = 1.f / (1.f + __expf(-x));
            const size_t idx = (size_t)bb * DD + d;
            const float rv = r[idx];
            const float hv = h[idx];
            out[idx] = (lb > 0) ? (hv + g * (rv - hv)) : hv;
        }
    }
}

extern "C" void kernel_launch(void* const* d_in, const int* in_sizes, int n_in,
                              void* d_out, int out_size, void* d_ws, size_t ws_size,
                              hipStream_t stream) {
    const float* h    = (const float*)d_in[0];
    const float* mem  = (const float*)d_in[1];
    const int*   len  = (const int*)d_in[2];
    const float* Wg_w = (const float*)d_in[3];
    const float* Wg_b = (const float*)d_in[4];
    const float* Ug_w = (const float*)d_in[5];
    const float* Ug_b = (const float*)d_in[6];
    const float* b_g  = (const float*)d_in[7];
    float* out  = (float*)d_out;
    float* r_ws = (float*)d_ws;   // B*D*4 = 8 MiB scratch for r

    attn_kernel<<<BB, 256, 0, stream>>>(h, mem, len, r_ws);
    gate_kernel<<<dim3(BB / 64, DD / 64), 256, 0, stream>>>(
        h, r_ws, len, Wg_w, Wg_b, Ug_w, Ug_b, b_g, out);
}